// Round 6
// baseline (238.895 us; speedup 1.0000x reference)
//
#include <hip/hip_runtime.h>
#include <math.h>

#define S_LEN 1024
#define DMODEL 1024

typedef __attribute__((ext_vector_type(8))) short bf16x8;
typedef __attribute__((ext_vector_type(4))) float f32x4;

#define MFMA16(a, b, c) __builtin_amdgcn_mfma_f32_16x16x32_bf16(a, b, c, 0, 0, 0)

#define WP (1024u * 1024u)       // W plane, ushorts (2 MB)
#define XP (4u * 1024u * 1024u)  // X/head plane, ushorts (8 MB)

// round-to-nearest-even fp32 -> bf16
__device__ __forceinline__ unsigned short rne_bf16(float f) {
    unsigned u = __float_as_uint(f);
    u += 0x7FFFu + ((u >> 16) & 1u);
    return (unsigned short)(u >> 16);
}

// ---------------------------------------------------------------------------
// Fragment-tiled ("swizzled") operand layout, shared by A and B operands of
// 16x16x32 bf16 MFMA:  plane[((tile16*32 + kt)*64 + kc*16 + r15)*8 + j]
// where element (row r, k) has tile16=r>>4, r15=r&15, kt=k>>5, kc=(k>>3)&3,
// j=k&7.  A wave's fragment load = 64 lanes x 16 B contiguous (1 KB).
// ---------------------------------------------------------------------------

// Converter: W planes (Wq/Wk/Wv hi; Wo hi+lo) and X planes (q/k/v rne) into
// fragment-tiled layout. Block = one 16-row x 1024-k panel; 8 chunks/thread.
// Reads 128B-granular, writes fully coalesced (4 KB contiguous per step).
__global__ __launch_bounds__(256)
void convert_sw(const float* __restrict__ W0, const float* __restrict__ W1,
                const float* __restrict__ W2, const float* __restrict__ W3,
                const float* __restrict__ Xq, const float* __restrict__ Xk,
                const float* __restrict__ Xv,
                unsigned short* __restrict__ Wsw, unsigned short* __restrict__ Xsw) {
    const int blk = blockIdx.x, t = threadIdx.x;
    const float* S;
    unsigned short* D;
    unsigned short* D2 = nullptr;
    int p;
    if (blk < 256) {  // W: 4 matrices x 64 panels
        const int which = blk >> 6;
        p = blk & 63;
        S = which == 0 ? W0 : which == 1 ? W1 : which == 2 ? W2 : W3;
        if (which == 3) { D = Wsw + 3 * WP; D2 = Wsw + 4 * WP; }
        else            { D = Wsw + (size_t)which * WP; }
    } else {          // X: 3 tensors x 256 panels
        const int which = (blk - 256) >> 8;
        p = (blk - 256) & 255;
        S = which == 0 ? Xq : which == 1 ? Xk : Xv;
        D = Xsw + (size_t)which * XP;
    }
    const int n15 = t & 15;
    const size_t rowOff = (size_t)(p * 16 + n15) * 1024;
    #pragma unroll
    for (int e = 0; e < 8; e++) {
        int kchunk = e * 16 + (t >> 4);    // 0..127
        int k0 = kchunk * 8;
        float4 f0 = *(const float4*)&S[rowOff + k0];
        float4 f1 = *(const float4*)&S[rowOff + k0 + 4];
        int kt = kchunk >> 2, kc = kchunk & 3;
        size_t dst = ((size_t)(p * 32 + kt) * 64 + kc * 16 + n15) * 8;
        float v[8] = {f0.x, f0.y, f0.z, f0.w, f1.x, f1.y, f1.z, f1.w};
        bf16x8 h;
        #pragma unroll
        for (int i = 0; i < 8; i++) h[i] = (short)rne_bf16(v[i]);
        *(bf16x8*)&D[dst] = h;
        if (D2) {
            bf16x8 l;
            #pragma unroll
            for (int i = 0; i < 8; i++) {
                float lf = v[i] - __uint_as_float(((unsigned)(unsigned short)h[i]) << 16);
                l[i] = (short)rne_bf16(lf);
            }
            *(bf16x8*)&D2[dst] = l;
        }
    }
}

// ---------------------------------------------------------------------------
// Fused Q/K/V projection, flatmm style: NO LDS, NO barriers. Operands read
// directly from fragment-tiled planes (coalesced 1 KB/frag), double-buffered
// in registers; 16 MFMAs per kt per wave. 128x128 tile, grid (8,32,3).
// Epilogue: z=0/1 rne -> [b][h][s][dh]; z=2 rne -> [b][h][dh][s].
// ---------------------------------------------------------------------------
__global__ __launch_bounds__(256)
void gemm_proj(const unsigned short* __restrict__ Xsw,
               const unsigned short* __restrict__ Wsw,
               unsigned short* __restrict__ Obase) {
    const int z = blockIdx.z;
    const unsigned short* A = Xsw + (size_t)z * XP;
    const unsigned short* B = Wsw + (size_t)z * WP;

    const int t = threadIdx.x, lane = t & 63, w = t >> 6;
    const int quad = lane >> 4, l15 = lane & 15;
    const int wr = w & 1, wc = w >> 1;
    const int mt0 = blockIdx.y * 8 + wr * 4;   // first of 4 m-tiles (16 rows each)
    const int nt0 = blockIdx.x * 8 + wc * 4;

    int aoff[4], boff[4];
    #pragma unroll
    for (int i = 0; i < 4; i++) {
        aoff[i] = ((mt0 + i) * 32 * 64 + lane) * 8;
        boff[i] = ((nt0 + i) * 32 * 64 + lane) * 8;
    }

    f32x4 acc[4][4] = {};
    bf16x8 a0[4], b0[4], a1[4], b1[4];

    #pragma unroll
    for (int i = 0; i < 4; i++) {
        a0[i] = *(const bf16x8*)&A[aoff[i]];
        b0[i] = *(const bf16x8*)&B[boff[i]];
    }

    for (int kt = 0; kt < 32; kt += 2) {
        #pragma unroll
        for (int i = 0; i < 4; i++) {
            a1[i] = *(const bf16x8*)&A[aoff[i] + (kt + 1) * 512];
            b1[i] = *(const bf16x8*)&B[boff[i] + (kt + 1) * 512];
        }
        #pragma unroll
        for (int j = 0; j < 4; j++)
            #pragma unroll
            for (int i = 0; i < 4; i++)
                acc[i][j] = MFMA16(a0[i], b0[j], acc[i][j]);
        if (kt + 2 < 32) {
            #pragma unroll
            for (int i = 0; i < 4; i++) {
                a0[i] = *(const bf16x8*)&A[aoff[i] + (kt + 2) * 512];
                b0[i] = *(const bf16x8*)&B[boff[i] + (kt + 2) * 512];
            }
        }
        #pragma unroll
        for (int j = 0; j < 4; j++)
            #pragma unroll
            for (int i = 0; i < 4; i++)
                acc[i][j] = MFMA16(a1[i], b1[j], acc[i][j]);
    }

    unsigned short* O = Obase + (size_t)z * XP;
    #pragma unroll
    for (int i = 0; i < 4; i++)
        #pragma unroll
        for (int j = 0; j < 4; j++)
            #pragma unroll
            for (int r = 0; r < 4; r++) {
                int m = blockIdx.y * 128 + wr * 64 + i * 16 + quad * 4 + r;
                int n = blockIdx.x * 128 + wc * 64 + j * 16 + l15;
                int bb = m >> 10, s = m & 1023, hh = n >> 6, dh = n & 63;
                size_t hb = ((size_t)(bb * 16 + hh)) << 16;
                unsigned short v = rne_bf16(acc[i][j][r]);
                if (z == 2) O[hb + (size_t)dh * 1024 + s] = v;
                else        O[hb + s * 64 + dh] = v;
            }
}

// ---------------------------------------------------------------------------
// Output projection, flatmm: C = WS * Wo^T, 2 MFMA passes (hi+lo Wo), fp32
// out. 128x128 tile, grid (8,32): 32 MFMAs / 12 frag loads per kt per wave.
// ---------------------------------------------------------------------------
__global__ __launch_bounds__(256)
void gemm_out2(const unsigned short* __restrict__ A,
               const unsigned short* __restrict__ Bh, const unsigned short* __restrict__ Bl,
               float* __restrict__ Cf) {
    const int t = threadIdx.x, lane = t & 63, w = t >> 6;
    const int quad = lane >> 4, l15 = lane & 15;
    const int wr = w & 1, wc = w >> 1;
    const int mt0 = blockIdx.y * 8 + wr * 4;
    const int nt0 = blockIdx.x * 8 + wc * 4;

    int aoff[4], boff[4];
    #pragma unroll
    for (int i = 0; i < 4; i++) {
        aoff[i] = ((mt0 + i) * 32 * 64 + lane) * 8;
        boff[i] = ((nt0 + i) * 32 * 64 + lane) * 8;
    }

    f32x4 acc[4][4] = {};
    bf16x8 a0[4], bh0[4], bl0[4], a1[4], bh1[4], bl1[4];

    #pragma unroll
    for (int i = 0; i < 4; i++) {
        a0[i]  = *(const bf16x8*)&A [aoff[i]];
        bh0[i] = *(const bf16x8*)&Bh[boff[i]];
        bl0[i] = *(const bf16x8*)&Bl[boff[i]];
    }

    for (int kt = 0; kt < 32; kt += 2) {
        #pragma unroll
        for (int i = 0; i < 4; i++) {
            a1[i]  = *(const bf16x8*)&A [aoff[i] + (kt + 1) * 512];
            bh1[i] = *(const bf16x8*)&Bh[boff[i] + (kt + 1) * 512];
            bl1[i] = *(const bf16x8*)&Bl[boff[i] + (kt + 1) * 512];
        }
        #pragma unroll
        for (int j = 0; j < 4; j++)
            #pragma unroll
            for (int i = 0; i < 4; i++) {
                acc[i][j] = MFMA16(a0[i], bh0[j], acc[i][j]);
                acc[i][j] = MFMA16(a0[i], bl0[j], acc[i][j]);
            }
        if (kt + 2 < 32) {
            #pragma unroll
            for (int i = 0; i < 4; i++) {
                a0[i]  = *(const bf16x8*)&A [aoff[i] + (kt + 2) * 512];
                bh0[i] = *(const bf16x8*)&Bh[boff[i] + (kt + 2) * 512];
                bl0[i] = *(const bf16x8*)&Bl[boff[i] + (kt + 2) * 512];
            }
        }
        #pragma unroll
        for (int j = 0; j < 4; j++)
            #pragma unroll
            for (int i = 0; i < 4; i++) {
                acc[i][j] = MFMA16(a1[i], bh1[j], acc[i][j]);
                acc[i][j] = MFMA16(a1[i], bl1[j], acc[i][j]);
            }
    }

    #pragma unroll
    for (int i = 0; i < 4; i++)
        #pragma unroll
        for (int j = 0; j < 4; j++)
            #pragma unroll
            for (int r = 0; r < 4; r++) {
                int m = blockIdx.y * 128 + wr * 64 + i * 16 + quad * 4 + r;
                int n = blockIdx.x * 128 + wc * 64 + j * 16 + l15;
                Cf[(size_t)m * 1024 + n] = acc[i][j][r];
            }
}

// ---------------------------------------------------------------------------
// Flash attention, no-max softmax (bounded scores), single-plane rne Q/K/V.
// Epilogue writes WS in fragment-tiled layout for the flat out-projection.
// ---------------------------------------------------------------------------
__global__ __launch_bounds__(256)
void attn_mfma(const unsigned short* __restrict__ Qr, const unsigned short* __restrict__ Kr,
               const unsigned short* __restrict__ Vt,
               const int* __restrict__ mask, const float* __restrict__ gamma,
               unsigned short* __restrict__ WSsw) {
    __shared__ int maskS[1024];
    __shared__ unsigned short Ks[64 * 72];      // [j][d]
    __shared__ unsigned short Vs[64 * 72];      // [d][j]
    __shared__ unsigned short Ph[4 * 16 * 72];  // per-wave [q][j]

    const int t = threadIdx.x, lane = t & 63, w = t >> 6;
    const int quad = lane >> 4, l15 = lane & 15;
    const int q0 = blockIdx.x * 64, h = blockIdx.y, b = blockIdx.z;
    const size_t hb = ((size_t)(b * 16 + h)) << 16;

    ((int4*)maskS)[t] = ((const int4*)(mask + b * 1024))[t];

    bf16x8 qhi[2];
    {
        const int qrow = q0 + w * 16 + l15;
        const size_t qb = hb + (size_t)qrow * 64 + quad * 8;
        qhi[0] = *(const bf16x8*)&Qr[qb];
        qhi[1] = *(const bf16x8*)&Qr[qb + 32];
    }

    f32x4 o[4] = {};
    float lsum[4] = {0.f, 0.f, 0.f, 0.f};

    __syncthreads();

    for (int jt = 0; jt < 16; jt++) {
        const int j0 = jt * 64;
        if (maskS[j0]) break;
        const bool partial = maskS[j0 + 63] != 0;
        __syncthreads();
        #pragma unroll
        for (int e = 0; e < 2; e++) {
            int lin = e * 256 + t;
            int c = lin & 7, row = lin >> 3;
            *(bf16x8*)&Ks[row * 72 + c * 8] =
                *(const bf16x8*)&Kr[hb + (size_t)(j0 + row) * 64 + c * 8];
            *(bf16x8*)&Vs[row * 72 + c * 8] =
                *(const bf16x8*)&Vt[hb + (size_t)row * 1024 + j0 + c * 8];
        }
        __syncthreads();

        f32x4 s4[4] = {};
        #pragma unroll
        for (int nj = 0; nj < 4; nj++) {
            int kr = (nj * 16 + l15) * 72 + quad * 8;
            #pragma unroll
            for (int kk = 0; kk < 2; kk++) {
                bf16x8 kv = *(const bf16x8*)&Ks[kr + kk * 32];
                s4[nj] = MFMA16(qhi[kk], kv, s4[nj]);
            }
        }

        if (partial) {
            #pragma unroll
            for (int nj = 0; nj < 4; nj++) {
                int mk = maskS[j0 + nj * 16 + l15];
                #pragma unroll
                for (int r = 0; r < 4; r++) {
                    float p = mk ? 0.f : __expf(s4[nj][r] * 0.125f);
                    lsum[r] += p;
                    Ph[(w * 16 + quad * 4 + r) * 72 + nj * 16 + l15] = rne_bf16(p);
                }
            }
        } else {
            #pragma unroll
            for (int nj = 0; nj < 4; nj++) {
                #pragma unroll
                for (int r = 0; r < 4; r++) {
                    float p = __expf(s4[nj][r] * 0.125f);
                    lsum[r] += p;
                    Ph[(w * 16 + quad * 4 + r) * 72 + nj * 16 + l15] = rne_bf16(p);
                }
            }
        }

        bf16x8 ph[2];
        #pragma unroll
        for (int ks = 0; ks < 2; ks++)
            ph[ks] = *(const bf16x8*)&Ph[(w * 16 + l15) * 72 + ks * 32 + quad * 8];
        #pragma unroll
        for (int dt = 0; dt < 4; dt++) {
            int vr = (dt * 16 + l15) * 72 + quad * 8;
            #pragma unroll
            for (int ks = 0; ks < 2; ks++) {
                bf16x8 vv = *(const bf16x8*)&Vs[vr + ks * 32];
                o[dt] = MFMA16(ph[ks], vv, o[dt]);
            }
        }
    }

    #pragma unroll
    for (int r = 0; r < 4; r++) {
        lsum[r] += __shfl_xor(lsum[r], 1);
        lsum[r] += __shfl_xor(lsum[r], 2);
        lsum[r] += __shfl_xor(lsum[r], 4);
        lsum[r] += __shfl_xor(lsum[r], 8);
    }

    // epilogue: WS in fragment-tiled layout. m = b*1024 + qrow, k = h*64 + dh.
    const float g = gamma[h];
    const int mt = ((b * 1024 + q0) >> 4) + w;
    #pragma unroll
    for (int r = 0; r < 4; r++) {
        const int m15 = quad * 4 + r;
        const float sc = g / lsum[r];
        #pragma unroll
        for (int dt = 0; dt < 4; dt++) {
            int kg = h * 64 + dt * 16 + l15;
            int kt = kg >> 5, kc = (kg >> 3) & 3, j = kg & 7;
            WSsw[((size_t)(mt * 32 + kt) * 64 + kc * 16 + m15) * 8 + j] =
                rne_bf16(o[dt][r] * sc);
        }
    }
}

// ---------------------------------------------------------------------------
extern "C" void kernel_launch(void* const* d_in, const int* in_sizes, int n_in,
                              void* d_out, int out_size, void* d_ws, size_t ws_size,
                              hipStream_t stream) {
    const float* query = (const float*)d_in[0];
    const float* key   = (const float*)d_in[1];
    const float* value = (const float*)d_in[2];
    const int*   mask  = (const int*)d_in[3];
    const float* Wq    = (const float*)d_in[4];
    const float* Wk    = (const float*)d_in[5];
    const float* Wv    = (const float*)d_in[6];
    const float* Wo    = (const float*)d_in[7];
    const float* gamma = (const float*)d_in[8];
    float* out = (float*)d_out;

    unsigned short* u = (unsigned short*)d_ws;
    // 58 MB layout (29M ushorts):
    unsigned short* Xsw  = u;           // Xq,Xk,Xv fragment-tiled (3 x XP)
    unsigned short* Obase = u + 3 * XP; // Qr, Kr, Vt head planes (3 x XP)
    unsigned short* Wsw  = u + 6 * XP;  // Wq,Wk,Wv hi + Wo hi,lo (5 x WP)
    unsigned short* WSsw = Xsw;         // alias: Xq-sw dead after gemm_proj
    unsigned short* Qr = Obase, *Kr = Obase + XP, *Vt = Obase + 2 * XP;
    unsigned short* Woh = Wsw + 3 * WP, *Wol = Wsw + 4 * WP;

    convert_sw<<<1024, 256, 0, stream>>>(Wq, Wk, Wv, Wo, query, key, value, Wsw, Xsw);

    gemm_proj<<<dim3(8, 32, 3), 256, 0, stream>>>(Xsw, Wsw, Obase);

    attn_mfma<<<dim3(16, 16, 4), 256, 0, stream>>>(Qr, Kr, Vt, mask, gamma, WSsw);

    gemm_out2<<<dim3(8, 32), 256, 0, stream>>>(WSsw, Woh, Wol, out);
}

// Round 7
// 217.069 us; speedup vs baseline: 1.1005x; 1.1005x over previous
//
#include <hip/hip_runtime.h>
#include <math.h>

typedef __attribute__((ext_vector_type(8))) short bf16x8;
typedef __attribute__((ext_vector_type(4))) short bf16x4;
typedef __attribute__((ext_vector_type(4))) float f32x4;

#define MFMA16(a, b, c) __builtin_amdgcn_mfma_f32_16x16x32_bf16(a, b, c, 0, 0, 0)

#define WPL (1024u * 1024u)       // W plane, ushorts (2 MB)
#define XPL (4u * 1024u * 1024u)  // X/head plane, ushorts (8 MB)

// round-to-nearest-even fp32 -> bf16
__device__ __forceinline__ unsigned short rne_bf16(float f) {
    unsigned u = __float_as_uint(f);
    u += 0x7FFFu + ((u >> 16) & 1u);
    return (unsigned short)(u >> 16);
}

// async global->LDS, 16B per lane. LDS dest = wave-uniform base + lane*16.
typedef const __attribute__((address_space(1))) unsigned int* gas_t;
typedef __attribute__((address_space(3))) unsigned int* las_t;
__device__ __forceinline__ void glds16(const void* g, void* l) {
    __builtin_amdgcn_global_load_lds((gas_t)g, (las_t)l, 16, 0, 0);
}

// ---------------------------------------------------------------------------
// Converter: Wq/Wk/Wv/Wo -> rne bf16 planes; query/key/value -> rne planes.
// All row-major. blocks 0..4095 = W, 4096..16383 = X.
// ---------------------------------------------------------------------------
__global__ __launch_bounds__(256)
void convert_all(const float* __restrict__ Wq, const float* __restrict__ Wk,
                 const float* __restrict__ Wv, const float* __restrict__ Wo,
                 const float* __restrict__ Xq, const float* __restrict__ Xk,
                 const float* __restrict__ Xv,
                 unsigned short* __restrict__ Wb, unsigned short* __restrict__ Xb) {
    int blk = blockIdx.x;
    const float* S;
    unsigned short* D;
    if (blk < 4096) {
        int which = blk >> 10;
        S = which == 0 ? Wq : which == 1 ? Wk : which == 2 ? Wv : Wo;
        D = Wb + (size_t)which * WPL;
        blk &= 1023;
    } else {
        blk -= 4096;
        int which = blk >> 12;
        S = which == 0 ? Xq : which == 1 ? Xk : Xv;
        D = Xb + (size_t)which * XPL;
        blk &= 4095;
    }
    int i = (blk * 256 + threadIdx.x) * 4;
    float4 f = *(const float4*)&S[i];
    bf16x4 h;
    h[0] = (short)rne_bf16(f.x);
    h[1] = (short)rne_bf16(f.y);
    h[2] = (short)rne_bf16(f.z);
    h[3] = (short)rne_bf16(f.w);
    *(bf16x4*)&D[i] = h;
}

// ---------------------------------------------------------------------------
// Universal single-pass GEMM: C[m][n] = sum_k A[m][k]*B[n][k], M=4096,
// N=K=1024, bf16 row-major A/B. 128x128 tile, BK=64, 4 waves (2x2 of 64x64).
// m97-style 2-barrier K-loop with global_load_lds dwordx4 staging.
// Additive bank swizzle: LDS slot s of row r holds global chunk (s+2r)&7
// -> frag ds_read_b128 bank groups (quad+4kk-l15)%8 are perfectly uniform.
// mode (modeBase+z): 0 Q->[b][h][s][dh]; 1 K->frag-tiled per head;
//                    2 V->frag-tiled transposed per head; 3 fp32 C row-major.
// ---------------------------------------------------------------------------
__global__ __launch_bounds__(256)
void gemm_ab(const unsigned short* __restrict__ Abase,
             const unsigned short* __restrict__ Bbase,
             unsigned short* __restrict__ QKV, float* __restrict__ Cf,
             int modeBase) {
    __shared__ unsigned short AS[128 * 64], BS[128 * 64];
    const int z = blockIdx.z, mode = modeBase + z;
    const unsigned short* A = Abase + (size_t)z * XPL;
    const unsigned short* B = Bbase + (size_t)z * WPL;

    const int t = threadIdx.x, lane = t & 63, w = t >> 6;
    const int quad = lane >> 4, l15 = lane & 15;
    const int wr = w & 1, wc = w >> 1;
    const int rowBase = blockIdx.y * 128, colBase = blockIdx.x * 128;

    // staging: instr e covers rows [e*32 + w*8, +8); lane -> (row: lane>>3,
    // slot: lane&7); global chunk cg = (slot + 2*row)&7 (coalesced per row).
    const int srow = lane >> 3;
    const int cg = ((lane & 7) + 2 * srow) & 7;
    const unsigned short *gA[4], *gB[4];
    unsigned short *lA[4], *lB[4];
    #pragma unroll
    for (int e = 0; e < 4; e++) {
        int row = e * 32 + w * 8 + srow;
        gA[e] = A + (size_t)(rowBase + row) * 1024 + cg * 8;
        gB[e] = B + (size_t)(colBase + row) * 1024 + cg * 8;
        lA[e] = &AS[(e * 32 + w * 8) * 64];
        lB[e] = &BS[(e * 32 + w * 8) * 64];
    }

    // fragment addresses: row ra needs global chunk kk*4+quad at LDS slot
    // (kk*4+quad-2*ra)&7; ra≡l15 (mod 8).
    const int s0 = (quad - 2 * l15) & 7;
    const int c0 = s0 * 8, c1 = ((s0 + 4) & 7) * 8;
    int aOff[4], bOff[4];
    #pragma unroll
    for (int i = 0; i < 4; i++) {
        aOff[i] = (wr * 64 + i * 16 + l15) * 64;
        bOff[i] = (wc * 64 + i * 16 + l15) * 64;
    }

    f32x4 acc[4][4] = {};

    for (int kt = 0; kt < 16; kt++) {
        if (kt) __syncthreads();
        const int ko = kt * 64;
        #pragma unroll
        for (int e = 0; e < 4; e++) {
            glds16(gA[e] + ko, lA[e]);
            glds16(gB[e] + ko, lB[e]);
        }
        __syncthreads();

        bf16x8 af[4], bfr[4];
        #pragma unroll
        for (int i = 0; i < 4; i++) af[i] = *(const bf16x8*)&AS[aOff[i] + c0];
        #pragma unroll
        for (int j = 0; j < 4; j++) bfr[j] = *(const bf16x8*)&BS[bOff[j] + c0];
        #pragma unroll
        for (int j = 0; j < 4; j++)
            #pragma unroll
            for (int i = 0; i < 4; i++)
                acc[i][j] = MFMA16(af[i], bfr[j], acc[i][j]);

        #pragma unroll
        for (int i = 0; i < 4; i++) af[i] = *(const bf16x8*)&AS[aOff[i] + c1];
        #pragma unroll
        for (int j = 0; j < 4; j++) bfr[j] = *(const bf16x8*)&BS[bOff[j] + c1];
        #pragma unroll
        for (int j = 0; j < 4; j++)
            #pragma unroll
            for (int i = 0; i < 4; i++)
                acc[i][j] = MFMA16(af[i], bfr[j], acc[i][j]);
    }

    // epilogue (C/D: col = lane&15, row = quad*4 + r)
    if (mode == 3) {
        #pragma unroll
        for (int i = 0; i < 4; i++)
            #pragma unroll
            for (int j = 0; j < 4; j++)
                #pragma unroll
                for (int r = 0; r < 4; r++) {
                    int m = rowBase + wr * 64 + i * 16 + quad * 4 + r;
                    int n = colBase + wc * 64 + j * 16 + l15;
                    Cf[(size_t)m * 1024 + n] = acc[i][j][r];
                }
    } else {
        unsigned short* O = QKV + (size_t)z * XPL;
        #pragma unroll
        for (int i = 0; i < 4; i++)
            #pragma unroll
            for (int j = 0; j < 4; j++)
                #pragma unroll
                for (int r = 0; r < 4; r++) {
                    int m = rowBase + wr * 64 + i * 16 + quad * 4 + r;
                    int n = colBase + wc * 64 + j * 16 + l15;
                    int bb = m >> 10, s = m & 1023, hh = n >> 6, dh = n & 63;
                    size_t hb = ((size_t)(bb * 16 + hh)) << 16;
                    unsigned short v = rne_bf16(acc[i][j][r]);
                    if (mode == 0) {
                        O[hb + s * 64 + dh] = v;             // Q row-major/head
                    } else if (mode == 1) {                  // K B-frag tiled
                        O[hb + (size_t)((s >> 4) * 2 + (dh >> 5)) * 512 +
                          ((dh >> 3) & 3) * 128 + (s & 15) * 8 + (dh & 7)] = v;
                    } else {                                 // V^T B-frag tiled
                        O[hb + (size_t)((dh >> 4) * 32 + (s >> 5)) * 512 +
                          ((s >> 3) & 3) * 128 + (dh & 15) * 8 + (s & 7)] = v;
                    }
                }
    }
}

// ---------------------------------------------------------------------------
// Flash attention, barrier-free K-loop: K/V fragments loaded straight from
// frag-tiled global planes (coalesced 1 KB per load, L2-resident). No-max
// softmax (scores bounded). Wave owns 32 q-rows; block = 128 q-rows.
// P round-trip through per-wave LDS with additive chunk swizzle.
// ---------------------------------------------------------------------------
__global__ __launch_bounds__(256)
void attn_flat(const unsigned short* __restrict__ Qp,
               const unsigned short* __restrict__ Kf,
               const unsigned short* __restrict__ Vf,
               const int* __restrict__ mask, const float* __restrict__ gamma,
               unsigned short* __restrict__ WSr) {
    __shared__ int maskS[1024];
    __shared__ unsigned short Ph[4][32 * 72];

    const int t = threadIdx.x, lane = t & 63, w = t >> 6;
    const int quad = lane >> 4, l15 = lane & 15;
    const int q0 = blockIdx.x * 128, h = blockIdx.y, b = blockIdx.z;
    const size_t hb = ((size_t)(b * 16 + h)) << 16;

    ((int4*)maskS)[t] = ((const int4*)(mask + b * 1024))[t];

    bf16x8 qf[2][2];
    #pragma unroll
    for (int mi = 0; mi < 2; mi++) {
        size_t qb = hb + (size_t)(q0 + w * 32 + mi * 16 + l15) * 64 + quad * 8;
        qf[mi][0] = *(const bf16x8*)&Qp[qb];
        qf[mi][1] = *(const bf16x8*)&Qp[qb + 32];
    }

    f32x4 o[2][4] = {};
    float lsum[2][4] = {{0.f, 0.f, 0.f, 0.f}, {0.f, 0.f, 0.f, 0.f}};
    unsigned short* P = Ph[w];

    __syncthreads();  // maskS ready (only block-wide sync in the kernel)

    for (int jt = 0; jt < 16; jt++) {
        const int j0 = jt * 64;
        if (maskS[j0]) break;  // monotonic mask
        const bool partial = maskS[j0 + 63] != 0;

        // K fragments (coalesced 1 KB each)
        bf16x8 kv[4][2];
        #pragma unroll
        for (int nj = 0; nj < 4; nj++)
            #pragma unroll
            for (int kk = 0; kk < 2; kk++)
                kv[nj][kk] = *(const bf16x8*)&Kf[hb + (size_t)((jt * 4 + nj) * 2 + kk) * 512 + lane * 8];

        f32x4 s4[2][4] = {};
        #pragma unroll
        for (int nj = 0; nj < 4; nj++)
            #pragma unroll
            for (int kk = 0; kk < 2; kk++)
                #pragma unroll
                for (int mi = 0; mi < 2; mi++)
                    s4[mi][nj] = MFMA16(qf[mi][kk], kv[nj][kk], s4[mi][nj]);

        // V fragments issued early (overlap with exp below)
        bf16x8 vv[4][2];
        #pragma unroll
        for (int dt = 0; dt < 4; dt++)
            #pragma unroll
            for (int ks = 0; ks < 2; ks++)
                vv[dt][ks] = *(const bf16x8*)&Vf[hb + (size_t)(dt * 32 + jt * 2 + ks) * 512 + lane * 8];

        // p = exp(s/8) (no max needed), write swizzled bf16 P
        #pragma unroll
        for (int mi = 0; mi < 2; mi++)
            #pragma unroll
            for (int nj = 0; nj < 4; nj++) {
                int mk = partial ? maskS[j0 + nj * 16 + l15] : 0;
                #pragma unroll
                for (int r = 0; r < 4; r++) {
                    float p = mk ? 0.f : __expf(s4[mi][nj][r] * 0.125f);
                    lsum[mi][r] += p;
                    int rowW = mi * 16 + quad * 4 + r;
                    int slot = ((nj * 2 + (l15 >> 3)) - 2 * rowW) & 7;
                    P[rowW * 72 + slot * 8 + (l15 & 7)] = rne_bf16(p);
                }
            }

        // P fragments (uniform bank groups), then O += P V
        bf16x8 pf[2][2];
        #pragma unroll
        for (int mi = 0; mi < 2; mi++) {
            int rowR = mi * 16 + l15;
            int sl0 = (quad - 2 * rowR) & 7;
            pf[mi][0] = *(const bf16x8*)&P[rowR * 72 + sl0 * 8];
            pf[mi][1] = *(const bf16x8*)&P[rowR * 72 + ((sl0 + 4) & 7) * 8];
        }
        #pragma unroll
        for (int dt = 0; dt < 4; dt++)
            #pragma unroll
            for (int ks = 0; ks < 2; ks++)
                #pragma unroll
                for (int mi = 0; mi < 2; mi++)
                    o[mi][dt] = MFMA16(pf[mi][ks], vv[dt][ks], o[mi][dt]);
    }

    #pragma unroll
    for (int mi = 0; mi < 2; mi++)
        #pragma unroll
        for (int r = 0; r < 4; r++) {
            lsum[mi][r] += __shfl_xor(lsum[mi][r], 1);
            lsum[mi][r] += __shfl_xor(lsum[mi][r], 2);
            lsum[mi][r] += __shfl_xor(lsum[mi][r], 4);
            lsum[mi][r] += __shfl_xor(lsum[mi][r], 8);
        }

    // epilogue: WS row-major [b*1024+s][h*64+dh], gamma/l fused
    const float g = gamma[h];
    #pragma unroll
    for (int mi = 0; mi < 2; mi++)
        #pragma unroll
        for (int r = 0; r < 4; r++) {
            int qrow = q0 + w * 32 + mi * 16 + quad * 4 + r;
            float sc = g / lsum[mi][r];
            size_t base = ((size_t)b * 1024 + qrow) * 1024 + h * 64;
            #pragma unroll
            for (int dt = 0; dt < 4; dt++)
                WSr[base + dt * 16 + l15] = rne_bf16(o[mi][dt][r] * sc);
        }
}

// ---------------------------------------------------------------------------
extern "C" void kernel_launch(void* const* d_in, const int* in_sizes, int n_in,
                              void* d_out, int out_size, void* d_ws, size_t ws_size,
                              hipStream_t stream) {
    const float* query = (const float*)d_in[0];
    const float* key   = (const float*)d_in[1];
    const float* value = (const float*)d_in[2];
    const int*   mask  = (const int*)d_in[3];
    const float* Wq    = (const float*)d_in[4];
    const float* Wk    = (const float*)d_in[5];
    const float* Wv    = (const float*)d_in[6];
    const float* Wo    = (const float*)d_in[7];
    const float* gamma = (const float*)d_in[8];
    float* out = (float*)d_out;

    unsigned short* u = (unsigned short*)d_ws;
    // 56 MB layout (28M ushorts):
    unsigned short* Xb  = u;            // Xq,Xk,Xv bf16 row-major (3 x XPL)
    unsigned short* QKV = u + 3 * XPL;  // Qp, Kf, Vf head planes (3 x XPL)
    unsigned short* Wb  = u + 6 * XPL;  // Wq,Wk,Wv,Wo bf16 row-major (4 x WPL)
    unsigned short* WSr = Xb;           // alias: Xq dead after proj
    unsigned short* Qp = QKV, *Kfp = QKV + XPL, *Vfp = QKV + 2 * XPL;
    unsigned short* Wob = Wb + 3 * WPL;

    convert_all<<<16384, 256, 0, stream>>>(Wq, Wk, Wv, Wo, query, key, value, Wb, Xb);

    gemm_ab<<<dim3(8, 32, 3), 256, 0, stream>>>(Xb, Wb, QKV, nullptr, 0);

    attn_flat<<<dim3(8, 16, 4), 256, 0, stream>>>(Qp, Kfp, Vfp, mask, gamma, WSr);

    gemm_ab<<<dim3(8, 32, 1), 256, 0, stream>>>(WSr, Wob, nullptr, out, 3);
}